// Round 5
// baseline (2600.222 us; speedup 1.0000x reference)
//
#include <hip/hip_runtime.h>

#define NDIM  2048
#define WAVES 32
#define SPW   2128            // steps per wave, padded (2112 + 16 slack)
#define BCOLS 2176
#define ENCB  0x40000000u
#define SENT  0xFFFFFFFFu

typedef unsigned long long u64;
typedef unsigned u32;

// Static scratch; prep rewrites everything it relies on, every launch.
__device__ __align__(16) float4 g_S[(size_t)WAVES * SPW * 64];     // sheared exp(theta)
__device__ __align__(16) u64    g_B[(size_t)(WAVES+1) * BCOLS * 2]; // boundary handoff

__device__ __forceinline__ u64 ald(const u64* p) {
  return __hip_atomic_load(p, __ATOMIC_RELAXED, __HIP_MEMORY_SCOPE_AGENT);
}
__device__ __forceinline__ void ast(u64* p, u64 v) {
  __hip_atomic_store(p, v, __ATOMIC_RELAXED, __HIP_MEMORY_SCOPE_AGENT);
}
__device__ __forceinline__ float shup1(float x) {   // lane n <- lane n-1 (lane0 <- 0)
  int v = __builtin_amdgcn_update_dpp(0, __float_as_int(x), 0x138, 0xf, 0xf, false);
  return __int_as_float(v);
}

// ------------- prep: shear + exp(theta) + boundary/sentinel init -----------
// S[w][t][L] = exp(theta[64w+L][t-L][:]) (float4-padded), 0 outside [0,2048).
__global__ void vit_prep(const float* __restrict__ theta) {
  const size_t total = (size_t)WAVES * SPW * 64;
  const size_t gstride = (size_t)gridDim.x * blockDim.x;
  for (size_t f = (size_t)blockIdx.x * blockDim.x + threadIdx.x; f < total; f += gstride) {
    const int L = (int)(f & 63);
    const size_t wt = f >> 6;
    const int t = (int)(wt % SPW);
    const int w = (int)(wt / SPW);
    const int c = t - L;
    float4 v = make_float4(0.f, 0.f, 0.f, 0.f);
    if (c >= 0 && c < NDIM) {
      const float* p = theta + ((size_t)(64*w + L) * NDIM + c) * 3;
      v.x = __expf(p[0]); v.y = __expf(p[1]); v.z = __expf(p[2]);
    }
    g_S[f] = v;
  }
  const int nb = (WAVES+1) * BCOLS;
  const u64 hi0 = ((u64)ENCB) << 32;   // (Y=0, e=0)
  for (int i = (int)(blockIdx.x * blockDim.x + threadIdx.x); i < nb; i += (int)gstride) {
    int w = i / BCOLS;
    int c = i - w * BCOLS;
    u64 lo, hi;
    if (c > NDIM)    { lo = 0ull; hi = hi0; }
    else if (w == 0) { lo = (c == 0) ? (u64)__float_as_uint(1.0f) : 0ull; hi = hi0; }
    else if (c == 0) { lo = 0ull; hi = hi0; }
    else             { lo = ~0ull; hi = ~0ull; }          // sentinel
    ast(&g_B[(size_t)i*2],   lo);
    ast(&g_B[(size_t)i*2+1], hi);
  }
}

// ---------------- main: 32 waves, striped wavefront, exp-space -------------
__global__ void __launch_bounds__(64, 1) vit_main(const float* __restrict__ A,
                                                  float* __restrict__ out) {
  __shared__ float4 sth[2][16*64];     // double-buffered epoch theta (32 KB)
  const int lane = threadIdx.x;
  const int w    = blockIdx.x;
  const bool isL0 = (lane == 0);

  const float a00 = __expf(A[0]), a01 = __expf(A[1]), a02 = __expf(A[2]);
  const float a10 = __expf(A[3]), a11 = __expf(A[4]), a12 = __expf(A[5]);
  const float a20 = __expf(A[6]), a21 = __expf(A[7]), a22 = __expf(A[8]);

  const float4* sb = g_S + (size_t)w * (SPW * 64);
  const u64* bin  = g_B + (size_t)w     * BCOLS * 2;
  u64*       bout = g_B + (size_t)(w+1) * BCOLS * 2;

  float Mp=0.f,Xp=0.f,Yp=0.f, Mu=0.f,Xu=0.f,Yu=0.f, Mud=0.f,Xud=0.f,Yud=0.f;
  int e_w = 0;
  uint4 bndA, bndB;

  // Stage epoch `ep` (16 steps x 1KB) into LDS buffer `buf` — direct to LDS,
  // no VGPR residency. Lane i's 16B lands at ldsbase + i*16 (verbatim copy).
  #define LDLDS(buf, ep) do {                                                  \
    const float4* _g = sb + (size_t)(ep) * (16*64) + lane;                     \
    _Pragma("unroll")                                                          \
    for (int _r = 0; _r < 16; ++_r)                                            \
      __builtin_amdgcn_global_load_lds(                                        \
        (const __attribute__((address_space(1))) void*)(_g + _r*64),           \
        (__attribute__((address_space(3))) void*)&sth[buf][_r*64], 16, 0, 0);  \
  } while (0)

  #define LDBND(dst, col0) do {                                                \
    int _c = (col0) + lane; if (_c > BCOLS-1) _c = BCOLS-1;                    \
    (dst) = *(const uint4*)(bin + (size_t)_c*2);                               \
  } while (0)

  // waitcnt vmcnt(50): exactly 50 vmem ops issue between an epoch's LDLDS and
  // this wait (1 bnd + 32 handoff stores + 16 next-epoch loads + 1 bnd);
  // in-order vmcnt retirement => target epoch's loads have landed. Spin-path
  // loads only push the target deeper (still safe). lgkm=15/exp=7 = no wait.
  #define WAITLDS() do {                                                       \
    __builtin_amdgcn_sched_barrier(0);                                         \
    __builtin_amdgcn_s_waitcnt(0xCF72);                                        \
    __builtin_amdgcn_sched_barrier(0);                                         \
  } while (0)

  #define RUN16(base, bufi, bnd) do {                                          \
    _Pragma("unroll")                                                          \
    for (int u = 0; u < 16; ++u) {                                             \
      const int s = (base) + u + 1;                                            \
      const float4 _t = sth[bufi][u*64 + lane];                                \
      const float T0 = _t.x, T1 = _t.y, T2 = _t.z;                             \
      float mn = T0 * fmaf(a02, Yud, fmaf(a01, Xud, a00*Mud));                 \
      float xn = T1 * fmaf(a12, Yu,  fmaf(a11, Xu,  a10*Mu));                  \
      float yn = T2 * fmaf(a22, Yp,  fmaf(a21, Xp,  a20*Mp));                  \
      if (s >= 64 && lane == 63) {                                             \
        u64 lo = ((u64)__float_as_uint(xn) << 32) | __float_as_uint(mn);       \
        u64 hi = ((u64)(u32)(e_w + (int)ENCB) << 32) | __float_as_uint(yn);    \
        u64* bo = bout + (size_t)(s - 63)*2;                                   \
        ast(bo, lo); ast(bo + 1, hi);                                          \
      }                                                                        \
      if (s == 2111 && w == WAVES-1 && lane == 63)                             \
        out[0] = (log2f(mn + xn + yn) + (float)e_w) * 0.69314718055994531f;    \
      u32 mbu = (u32)__builtin_amdgcn_readlane((int)(bnd).x, u);               \
      u32 xbu = (u32)__builtin_amdgcn_readlane((int)(bnd).y, u);               \
      u32 ybu = (u32)__builtin_amdgcn_readlane((int)(bnd).z, u);               \
      u32 ebu = (u32)__builtin_amdgcn_readlane((int)(bnd).w, u);               \
      if (mbu == SENT || xbu == SENT || ybu == SENT || ebu == SENT) {          \
        const u64* pl = bin + (size_t)(s + 1)*2;                               \
        u64 lo, hi;                                                            \
        for (;;) {                                                             \
          lo = ald(pl); hi = ald(pl + 1);                                      \
          if ((u32)lo != SENT && (u32)(lo>>32) != SENT &&                      \
              (u32)hi != SENT && (u32)(hi>>32) != SENT) break;                 \
          __builtin_amdgcn_s_sleep(1);                                         \
        }                                                                      \
        mbu = (u32)lo; xbu = (u32)(lo>>32); ybu = (u32)hi; ebu = (u32)(hi>>32);\
      }                                                                        \
      int d = (int)(ebu - ENCB) - e_w;                                         \
      d = __builtin_amdgcn_readfirstlane(d);                                   \
      if (d > 48) {                                                            \
        const int ep = (int)(ebu - ENCB);                                      \
        const int sh = e_w - ep;                                               \
        mn = ldexpf(mn,sh); xn = ldexpf(xn,sh); yn = ldexpf(yn,sh);            \
        Mu = ldexpf(Mu,sh); Xu = ldexpf(Xu,sh); Yu = ldexpf(Yu,sh);            \
        e_w = ep; d = 0;                                                       \
      }                                                                        \
      Mud = Mu; Xud = Xu; Yud = Yu;                                            \
      const float sm = shup1(mn), sx = shup1(xn), sy = shup1(yn);              \
      Mu = isL0 ? ldexpf(__uint_as_float(mbu), d) : sm;                        \
      Xu = isL0 ? ldexpf(__uint_as_float(xbu), d) : sx;                        \
      Yu = isL0 ? ldexpf(__uint_as_float(ybu), d) : sy;                        \
      Mp = mn; Xp = xn; Yp = yn;                                               \
    } } while (0)

  #define RESCALE(base) do {                                                   \
    float m = fmaxf(fmaxf(Mp, Xp), Yp);                                        \
    const int jl = (base) + 16 - lane;                                         \
    if (jl < 1 || jl > NDIM) m = 0.0f;                                         \
    _Pragma("unroll")                                                          \
    for (int off = 1; off < 64; off <<= 1) m = fmaxf(m, __shfl_xor(m, off));   \
    int E = (int)((__float_as_uint(m) >> 23) & 0xFF) - 127;                    \
    if (m == 0.0f) E = 0;                                                      \
    const int sh = -E;                                                         \
    Mp = ldexpf(Mp,sh); Xp = ldexpf(Xp,sh); Yp = ldexpf(Yp,sh);                \
    Mu = ldexpf(Mu,sh); Xu = ldexpf(Xu,sh); Yu = ldexpf(Yu,sh);                \
    Mud= ldexpf(Mud,sh);Xud= ldexpf(Xud,sh);Yud= ldexpf(Yud,sh);               \
    e_w += E;                                                                  \
  } while (0)

  // prologue: epoch 0 into buf0, first boundary batch, col 0/1 state
  LDLDS(0, 0);
  LDBND(bndA, 2);
  {
    u64 lo = ald(bin), hi = ald(bin + 1);   // col 0: prefilled, never sentinel
    if (isL0) {
      Mud = __uint_as_float((u32)lo);
      Xud = __uint_as_float((u32)(lo >> 32));
      Yud = __uint_as_float((u32)hi);
    }
  }
  {
    u64 lo, hi;                              // col 1: spin = pipeline fill
    for (;;) {
      lo = ald(bin + 2); hi = ald(bin + 3);
      if ((u32)lo != SENT && (u32)(lo>>32) != SENT &&
          (u32)hi != SENT && (u32)(hi>>32) != SENT) break;
      __builtin_amdgcn_s_sleep(4);
    }
    int ep = (int)((u32)(hi >> 32) - ENCB);
    int dd = ep - e_w;
    dd = __builtin_amdgcn_readfirstlane(dd);
    if (dd > 48) { e_w = ep; dd = 0; }
    if (isL0) {
      Mu = ldexpf(__uint_as_float((u32)lo), dd);
      Xu = ldexpf(__uint_as_float((u32)(lo >> 32)), dd);
      Yu = ldexpf(__uint_as_float((u32)hi), dd);
    }
  }
  // full drain so the loop's vmcnt(50) invariant starts clean (buf0 ready)
  __builtin_amdgcn_sched_barrier(0);
  __builtin_amdgcn_s_waitcnt(0x0F70);
  __builtin_amdgcn_sched_barrier(0);

  for (int base = 0; base < 2112; base += 32) {
    const int ep0 = base >> 4;            // even epoch -> buf0
    LDLDS(1, ep0 + 1);                    // next epoch into buf1
    LDBND(bndB, base + 18);               // cols for RUN16(base+16)
    WAITLDS();
    RUN16(base, 0, bndA);
    RESCALE(base);

    LDLDS(0, ep0 + 2);                    // epoch after next into buf0
    LDBND(bndA, base + 34);               // cols for RUN16(base+32)
    WAITLDS();
    RUN16(base + 16, 1, bndB);
    RESCALE(base + 16);
  }
  #undef LDLDS
  #undef LDBND
  #undef WAITLDS
  #undef RUN16
  #undef RESCALE
}

extern "C" void kernel_launch(void* const* d_in, const int* in_sizes, int n_in,
                              void* d_out, int out_size, void* d_ws, size_t ws_size,
                              hipStream_t stream) {
  const float* theta = (const float*)d_in[0];
  const float* A     = (const float*)d_in[1];
  float* out = (float*)d_out;
  (void)in_sizes; (void)n_in; (void)out_size; (void)d_ws; (void)ws_size;
  vit_prep<<<dim3(17024), dim3(256), 0, stream>>>(theta);
  vit_main<<<dim3(WAVES), dim3(64), 0, stream>>>(A, out);
}

// Round 7
// 970.772 us; speedup vs baseline: 2.6785x; 2.6785x over previous
//
#include <hip/hip_runtime.h>

#define NDIM  2048
#define WAVES 32
#define SPW   2128            // sheared steps per wave (2112 + 16 slack)
#define BCOLS 2176
#define ENCB  0x40000000u
#define SENT  0xFFFFFFFFu

typedef unsigned long long u64;
typedef unsigned u32;

// Static scratch; prep rewrites everything it relies on, every launch.
__device__ __align__(16) float4 g_S[(size_t)WAVES * SPW * 64];      // sheared exp(theta)
__device__ __align__(16) u64    g_B[(size_t)(WAVES+1) * BCOLS * 2]; // boundary handoff

__device__ __forceinline__ u64 ald(const u64* p) {
  return __hip_atomic_load(p, __ATOMIC_RELAXED, __HIP_MEMORY_SCOPE_AGENT);
}
__device__ __forceinline__ void ast(u64* p, u64 v) {
  __hip_atomic_store(p, v, __ATOMIC_RELAXED, __HIP_MEMORY_SCOPE_AGENT);
}
__device__ __forceinline__ float shup1(float x) {   // lane n <- lane n-1 (lane0 <- 0)
  int v = __builtin_amdgcn_update_dpp(0, __float_as_int(x), 0x138, 0xf, 0xf, false);
  return __int_as_float(v);
}
template <int CTRL>
__device__ __forceinline__ float dppmaxstep(float x) {
  int v = __builtin_amdgcn_update_dpp(__float_as_int(x), __float_as_int(x),
                                      CTRL, 0xf, 0xf, false);
  return fmaxf(x, __int_as_float(v));
}
// wave64 max -> result in lane 63, fetched via readlane (all-VALU, no LDS)
__device__ __forceinline__ float wave_max64(float x) {
  x = dppmaxstep<0x111>(x);  // row_shr:1
  x = dppmaxstep<0x112>(x);  // row_shr:2
  x = dppmaxstep<0x114>(x);  // row_shr:4
  x = dppmaxstep<0x118>(x);  // row_shr:8
  x = dppmaxstep<0x142>(x);  // row_bcast:15
  x = dppmaxstep<0x143>(x);  // row_bcast:31
  return __int_as_float(__builtin_amdgcn_readlane(__float_as_int(x), 63));
}

// ------------- prep: shear + exp(theta);  S[w][t][L] = exp(theta[64w+L][t-L]) -------------
// grid (SPW/16, WAVES), block (64,4): per block 16 t's x 64 lanes; lane L reads
// 16 x 12B contiguous from its row (good line reuse), writes coalesced 1KB/t.
__global__ void vit_prep(const float* __restrict__ theta) {
  const int L  = threadIdx.x;
  const int w  = blockIdx.y;
  const int t0 = blockIdx.x * 16;
  const float* rp = theta + (size_t)(64*w + L) * (NDIM*3);
  float4* op = g_S + ((size_t)w*SPW + t0)*64 + L;
  #pragma unroll
  for (int k = 0; k < 4; ++k) {
    const int q = threadIdx.y + 4*k;
    const int c = t0 + q - L;
    float4 v = make_float4(0.f, 0.f, 0.f, 0.f);
    if (c >= 0 && c < NDIM) {
      v.x = __expf(rp[c*3]); v.y = __expf(rp[c*3+1]); v.z = __expf(rp[c*3+2]);
    }
    op[(size_t)q*64] = v;
  }
}

__global__ void vit_binit() {
  const int i = blockIdx.x * 256 + threadIdx.x;
  const int nb = (WAVES+1) * BCOLS;
  if (i >= nb) return;
  const int w = i / BCOLS;
  const int c = i - w * BCOLS;
  const u64 hi0 = ((u64)ENCB) << 32;   // (Y=0, e=0)
  u64 lo, hi;
  if (c > NDIM)    { lo = 0ull; hi = hi0; }
  else if (w == 0) { lo = (c == 0) ? (u64)__float_as_uint(1.0f) : 0ull; hi = hi0; }
  else if (c == 0) { lo = 0ull; hi = hi0; }
  else             { lo = ~0ull; hi = ~0ull; }          // sentinel
  ast(&g_B[(size_t)i*2],   lo);
  ast(&g_B[(size_t)i*2+1], hi);
}

// ---------------- main: 32 waves, striped wavefront, exp-space -------------
__global__ void __launch_bounds__(64, 1) vit_main(const float* __restrict__ A,
                                                  float* __restrict__ out) {
  __shared__ float4 sth[2][16*64];     // double-buffered epoch theta (32 KB)
  const int lane = threadIdx.x;
  const int w    = blockIdx.x;
  const bool isL0 = (lane == 0);

  const float a00 = __expf(A[0]), a01 = __expf(A[1]), a02 = __expf(A[2]);
  const float a10 = __expf(A[3]), a11 = __expf(A[4]), a12 = __expf(A[5]);
  const float a20 = __expf(A[6]), a21 = __expf(A[7]), a22 = __expf(A[8]);

  const float4* sb = g_S + (size_t)w * (SPW * 64);
  const u64* bin  = g_B + (size_t)w     * BCOLS * 2;
  u64*       bout = g_B + (size_t)(w+1) * BCOLS * 2;

  float Mp=0.f,Xp=0.f,Yp=0.f, Mu=0.f,Xu=0.f,Yu=0.f, Mud=0.f,Xud=0.f,Yud=0.f;
  int e_w = 0;
  uint4 bndA, bndB;

  #define LDLDS(buf, ep) do {                                                  \
    const int _e = (ep) > 132 ? 132 : (ep);                                    \
    const float4* _g = sb + (size_t)_e * (16*64) + lane;                       \
    _Pragma("unroll")                                                          \
    for (int _r = 0; _r < 16; ++_r)                                            \
      __builtin_amdgcn_global_load_lds(                                        \
        (const __attribute__((address_space(1))) void*)(_g + _r*64),           \
        (__attribute__((address_space(3))) void*)&sth[buf][_r*64], 16, 0, 0);  \
  } while (0)

  // lanes 0..15 carry cols col0..col0+15 (other lanes duplicate -> same lines)
  #define LDBND(dst, col0) do {                                                \
    (dst) = *(const uint4*)(bin + (size_t)((col0) + (lane & 15))*2);           \
  } while (0)

  // parallel verified-batch: one wave-wide reload per retry, never per-column
  #define VERIFY(bnd, col0) do {                                               \
    const u64* _pp = bin + (size_t)((col0) + (lane & 15))*2;                   \
    bool _bad = ((bnd).x==SENT)|((bnd).y==SENT)|((bnd).z==SENT)|((bnd).w==SENT);\
    while (__any(_bad)) {                                                      \
      __builtin_amdgcn_s_sleep(2);                                             \
      u64 _lo = ald(_pp), _hi = ald(_pp + 1);                                  \
      (bnd).x=(u32)_lo; (bnd).y=(u32)(_lo>>32);                                \
      (bnd).z=(u32)_hi; (bnd).w=(u32)(_hi>>32);                                \
      _bad = ((bnd).x==SENT)|((bnd).y==SENT)|((bnd).z==SENT)|((bnd).w==SENT);  \
    } } while (0)

  // exactly 17 prefetch ops (16 LDLDS + 1 LDBND) are the newest vmem ops at
  // epoch top -> vmcnt(17) retires everything older (theta buf + stores).
  #define WAITV() do {                                                         \
    __builtin_amdgcn_sched_barrier(0);                                         \
    __builtin_amdgcn_s_waitcnt(0x4F71);   /* vmcnt(17) */                      \
    __builtin_amdgcn_sched_barrier(0);                                         \
  } while (0)

  #define RUN16(base, bufi, bnd) do {                                          \
    _Pragma("unroll")                                                          \
    for (int u = 0; u < 16; ++u) {                                             \
      const int s = (base) + u + 1;                                            \
      const float4 _t = sth[bufi][u*64 + lane];                                \
      const float T0 = _t.x, T1 = _t.y, T2 = _t.z;                             \
      float mn = T0 * fmaf(a02, Yud, fmaf(a01, Xud, a00*Mud));                 \
      float xn = T1 * fmaf(a12, Yu,  fmaf(a11, Xu,  a10*Mu));                  \
      float yn = T2 * fmaf(a22, Yp,  fmaf(a21, Xp,  a20*Mp));                  \
      if (s >= 64 && lane == 63) {                                             \
        u64 lo = ((u64)__float_as_uint(xn) << 32) | __float_as_uint(mn);       \
        u64 hi = ((u64)(u32)(e_w + (int)ENCB) << 32) | __float_as_uint(yn);    \
        u64* bo = bout + (size_t)(s - 63)*2;                                   \
        ast(bo, lo); ast(bo + 1, hi);                                          \
      }                                                                        \
      if (s == 2111 && w == WAVES-1 && lane == 63)                             \
        out[0] = (log2f(mn + xn + yn) + (float)e_w) * 0.69314718055994531f;    \
      const u32 mbu = (u32)__builtin_amdgcn_readlane((int)(bnd).x, u);         \
      const u32 xbu = (u32)__builtin_amdgcn_readlane((int)(bnd).y, u);         \
      const u32 ybu = (u32)__builtin_amdgcn_readlane((int)(bnd).z, u);         \
      const u32 ebu = (u32)__builtin_amdgcn_readlane((int)(bnd).w, u);         \
      int d = (int)(ebu - ENCB) - e_w;                                         \
      if (d > 48) {                                                            \
        const int ep = (int)(ebu - ENCB);                                      \
        const int sh = e_w - ep;                                               \
        mn = ldexpf(mn,sh); xn = ldexpf(xn,sh); yn = ldexpf(yn,sh);            \
        Mu = ldexpf(Mu,sh); Xu = ldexpf(Xu,sh); Yu = ldexpf(Yu,sh);            \
        e_w = ep; d = 0;                                                       \
      }                                                                        \
      Mud = Mu; Xud = Xu; Yud = Yu;                                            \
      const float sm = shup1(mn), sx = shup1(xn), sy = shup1(yn);              \
      Mu = isL0 ? ldexpf(__uint_as_float(mbu), d) : sm;                        \
      Xu = isL0 ? ldexpf(__uint_as_float(xbu), d) : sx;                        \
      Yu = isL0 ? ldexpf(__uint_as_float(ybu), d) : sy;                        \
      Mp = mn; Xp = xn; Yp = yn;                                               \
    } } while (0)

  #define RESCALE(base) do {                                                   \
    float m = fmaxf(fmaxf(Mp, Xp), Yp);                                        \
    const int jl = (base) + 16 - lane;                                         \
    if (jl < 1 || jl > NDIM) m = 0.0f;                                         \
    m = wave_max64(m);                                                         \
    int E = (int)((__float_as_uint(m) >> 23) & 0xFF) - 127;                    \
    if (m == 0.0f) E = 0;                                                      \
    const int sh = -E;                                                         \
    Mp = ldexpf(Mp,sh); Xp = ldexpf(Xp,sh); Yp = ldexpf(Yp,sh);                \
    Mu = ldexpf(Mu,sh); Xu = ldexpf(Xu,sh); Yu = ldexpf(Yu,sh);                \
    Mud= ldexpf(Mud,sh);Xud= ldexpf(Xud,sh);Yud= ldexpf(Yud,sh);               \
    e_w += E;                                                                  \
  } while (0)

  // ---- prologue ----
  LDLDS(0, 0); LDLDS(1, 1);
  LDBND(bndA, 2);    // epoch 0 cols
  LDBND(bndB, 18);   // epoch 1 cols
  {
    u64 lo = ald(bin), hi = ald(bin + 1);   // col 0: prefilled, never sentinel
    if (isL0) {
      Mud = __uint_as_float((u32)lo);
      Xud = __uint_as_float((u32)(lo >> 32));
      Yud = __uint_as_float((u32)hi);
    }
  }
  {
    u64 lo, hi;                              // col 1: spin = pipeline fill
    for (;;) {
      lo = ald(bin + 2); hi = ald(bin + 3);
      if ((u32)lo != SENT && (u32)(lo>>32) != SENT &&
          (u32)hi != SENT && (u32)(hi>>32) != SENT) break;
      __builtin_amdgcn_s_sleep(4);
    }
    int ep = (int)((u32)(hi >> 32) - ENCB);
    int dd = ep - e_w;
    dd = __builtin_amdgcn_readfirstlane(dd);
    if (dd > 48) { e_w = ep; dd = 0; }
    if (isL0) {
      Mu = ldexpf(__uint_as_float((u32)lo), dd);
      Xu = ldexpf(__uint_as_float((u32)(lo >> 32)), dd);
      Yu = ldexpf(__uint_as_float((u32)hi), dd);
    }
  }
  VERIFY(bndA, 2);
  __builtin_amdgcn_sched_barrier(0);
  __builtin_amdgcn_s_waitcnt(0x0F70);        // vmcnt(0): buf0 ready
  __builtin_amdgcn_sched_barrier(0);
  LDLDS(1, 1);                                // re-issue so loop-top vmcnt(17)
  LDBND(bndB, 18);                            // invariant holds exactly

  // ---- main loop: 132 epochs, x2 unrolled for buffer/batch ping-pong ----
  for (int e = 0; e < 132; e += 2) {
    const int b0 = 16*e;
    WAITV();
    RUN16(b0, 0, bndA);
    RESCALE(b0);
    VERIFY(bndB, b0 + 18);
    LDLDS(0, e + 2);
    LDBND(bndA, b0 + 34);

    WAITV();
    RUN16(b0 + 16, 1, bndB);
    RESCALE(b0 + 16);
    VERIFY(bndA, b0 + 34);
    LDLDS(1, e + 3);
    LDBND(bndB, b0 + 50);
  }
  #undef LDLDS
  #undef LDBND
  #undef VERIFY
  #undef WAITV
  #undef RUN16
  #undef RESCALE
}

extern "C" void kernel_launch(void* const* d_in, const int* in_sizes, int n_in,
                              void* d_out, int out_size, void* d_ws, size_t ws_size,
                              hipStream_t stream) {
  const float* theta = (const float*)d_in[0];
  const float* A     = (const float*)d_in[1];
  float* out = (float*)d_out;
  (void)in_sizes; (void)n_in; (void)out_size; (void)d_ws; (void)ws_size;
  vit_prep<<<dim3(SPW/16, WAVES), dim3(64, 4), 0, stream>>>(theta);
  vit_binit<<<dim3(((WAVES+1)*BCOLS + 255)/256), dim3(256), 0, stream>>>();
  vit_main<<<dim3(WAVES), dim3(64), 0, stream>>>(A, out);
}